// Round 3
// baseline (273.102 us; speedup 1.0000x reference)
//
#include <hip/hip_runtime.h>
#include <math.h>

#define NN 50000
#define NE 800000
// IN=256, MAP=64, H=4, O=64
#define LEAKY 0.2f
#define NT 26              // 26 column tiles of 16 (416 cols, 400 real)
#define CAP 96             // padded CSR slots/node (max deg over Poisson(16) << 96)
#define NBT (8 * NT * 64)  // Btf fragment count
#define BT_BLKS 54         // (NBT+512)/256 exactly

typedef short bf16x8 __attribute__((ext_vector_type(8)));
typedef float f32x4 __attribute__((ext_vector_type(4)));
typedef float f32x2 __attribute__((ext_vector_type(2)));

__device__ __forceinline__ unsigned short f2bf(float f) {
  unsigned u = __float_as_uint(f);
  u += 0x7fffu + ((u >> 16) & 1u);
  return (unsigned short)(u >> 16);
}
__device__ __forceinline__ float leaky(float v) { return v > 0.0f ? v : LEAKY * v; }
__device__ __forceinline__ float rlf(float v, int l) {
  return __uint_as_float(__builtin_amdgcn_readlane(__float_as_uint(v), l));
}
__device__ __forceinline__ int rli(int v, int l) {
  return __builtin_amdgcn_readlane(v, l);
}

// packed f32->bf16 (RNE) x8 via HW cvt; returns MFMA A/B fragment
__device__ __forceinline__ bf16x8 ld_a_bf16(const float* p) {
  float4 fa = *(const float4*)p;
  float4 fb = *(const float4*)(p + 4);
  unsigned r0, r1, r2, r3;
  asm("v_cvt_pk_bf16_f32 %0, %1, %2" : "=v"(r0) : "v"(fa.x), "v"(fa.y));
  asm("v_cvt_pk_bf16_f32 %0, %1, %2" : "=v"(r1) : "v"(fa.z), "v"(fa.w));
  asm("v_cvt_pk_bf16_f32 %0, %1, %2" : "=v"(r2) : "v"(fb.x), "v"(fb.y));
  asm("v_cvt_pk_bf16_f32 %0, %1, %2" : "=v"(r3) : "v"(fb.z), "v"(fb.w));
  union { uint4 u; bf16x8 v; } c;
  c.u = make_uint4(r0, r1, r2, r3);
  return c.v;
}

// ---- fp8 e4m3fn helpers (HW cvt on gfx950; software fallback) ----
#if defined(__has_builtin)
#if __has_builtin(__builtin_amdgcn_cvt_pk_f32_fp8) && \
    __has_builtin(__builtin_amdgcn_cvt_pk_fp8_f32) && \
    __has_builtin(__builtin_amdgcn_cvt_f32_fp8)
#define FP8_HW 1
#endif
#endif

#ifdef FP8_HW
__device__ __forceinline__ unsigned char f2fp8(float v) {
  return (unsigned char)(__builtin_amdgcn_cvt_pk_fp8_f32(v, v, 0u, false) & 0xFF);
}
__device__ __forceinline__ f32x2 fp8x2_lo(unsigned int v) {
  return __builtin_amdgcn_cvt_pk_f32_fp8(v, false);   // word-select must be literal
}
__device__ __forceinline__ f32x2 fp8x2_hi(unsigned int v) {
  return __builtin_amdgcn_cvt_pk_f32_fp8(v, true);
}
__device__ __forceinline__ float fp8one(unsigned int v) {
  return __builtin_amdgcn_cvt_f32_fp8(v, 0);
}
#else
__device__ __forceinline__ unsigned char f2fp8(float f) {
  unsigned u = __float_as_uint(f);
  unsigned s = (u >> 31) << 7;
  unsigned a = u & 0x7FFFFFFFu;
  if (a >= 0x43E00000u) return (unsigned char)(s | 0x7E);
  if (a < 0x3C800000u) {
    float m = __uint_as_float(a) * 512.0f;
    int q = (int)(m + 0.5f); if (q > 7) q = 7;
    return (unsigned char)(s | q);
  }
  a += 0x7FFFFu + ((a >> 20) & 1);
  unsigned e = ((a >> 23) & 0xFF) - 120;
  if (e > 15) return (unsigned char)(s | 0x7E);
  return (unsigned char)(s | (e << 3) | ((a >> 20) & 7));
}
__device__ __forceinline__ float fp8dec1(unsigned b) {
  unsigned s = (b & 0x80u) << 24;
  unsigned em = b & 0x7Fu;
  unsigned e4 = em >> 3, m3 = em & 7;
  float v = e4 ? __uint_as_float(((e4 + 120) << 23) | (m3 << 20))
               : (float)m3 * 0.001953125f;
  return __uint_as_float(__float_as_uint(v) ^ s);
}
__device__ __forceinline__ f32x2 fp8x2_lo(unsigned int v) {
  f32x2 r; r[0] = fp8dec1(v & 0xFF); r[1] = fp8dec1((v >> 8) & 0xFF); return r;
}
__device__ __forceinline__ f32x2 fp8x2_hi(unsigned int v) {
  f32x2 r; r[0] = fp8dec1((v >> 16) & 0xFF); r[1] = fp8dec1((v >> 24) & 0xFF); return r;
}
__device__ __forceinline__ float fp8one(unsigned int v) { return fp8dec1(v & 0xFF); }
#endif

// Panel columns (416 = 26 tiles of 16):
//  c in 0..255   : feat, PERMUTED: panel col c holds W_gat column (c&3)*64 + (c>>2)
//                  so the GEMM output is featq[row][o*4+h] (o=c>>2, h=c&3)
//  c in 256..319 : gate_m_W (z)
//  c in 320..383 : merge_W[0:256] (xm)
//  c in 384..387 : gate_fn_W x-part (gx)
//  c in 388..391 : gate_fn_W mean-part (u)
//  c >= 392      : zero pad
__device__ __forceinline__ float panel_w(int col, int k,
    const float* W_gat, const float* gate_m_W, const float* merge_W,
    const float* gate_fn_W) {
  if (col < 256)      return W_gat[k * 256 + (col & 3) * 64 + (col >> 2)];
  else if (col < 320) return gate_m_W[k * 64 + (col - 256)];
  else if (col < 384) return merge_W[k * 64 + (col - 320)];
  else if (col < 388) return gate_fn_W[k * 4 + (col - 384)];
  else if (col < 392) return gate_fn_W[(320 + k) * 4 + (col - 388)];
  return 0.0f;
}

// Weight prep: Btf + mWf fragments, sentinels.  (x is consumed directly by the GEMM;
// cursor zeroing moved to hipMemsetAsync.)
__global__ __launch_bounds__(256) void k_prep(
    const float* __restrict__ W_gat, const float* __restrict__ gate_m_W,
    const float* __restrict__ merge_W, const float* __restrict__ gate_fn_W,
    unsigned short* __restrict__ Btf, unsigned short* __restrict__ mWf,
    unsigned char* __restrict__ zq, float* __restrict__ epay,
    unsigned char* __restrict__ featq) {
  int b = blockIdx.x, tid = threadIdx.x;
  int idx = b * 256 + tid;
  if (idx < NBT) {
    int kq = idx / (NT * 64);
    int rem = idx - kq * (NT * 64);
    int t = rem >> 6, lane = rem & 63;
    int col = t * 16 + (lane & 15);
    int k = kq * 32 + (lane >> 4) * 8;
    unsigned short* o = Btf + (size_t)idx * 8;
#pragma unroll
    for (int i = 0; i < 8; ++i)
      o[i] = f2bf(panel_w(col, k + i, W_gat, gate_m_W, merge_W, gate_fn_W));
  } else if (idx < NBT + 512) {
    int idx2 = idx - NBT;
    int kq = idx2 >> 8;
    int rem = idx2 & 255;
    int t = rem >> 6, lane = rem & 63;
    int col = t * 16 + (lane & 15);
    int k = kq * 32 + ((lane >> 4) & 3) * 8;
    unsigned short* o = mWf + (size_t)idx2 * 8;
#pragma unroll
    for (int i = 0; i < 8; ++i)
      o[i] = f2bf(merge_W[(size_t)(256 + k + i) * 64 + col]);
  } else if (b == BT_BLKS) {
    if (tid < 64) zq[(size_t)NN * 64 + tid] = 0xFE;   // sentinel z = -448
    if (tid < 8) epay[(size_t)NN * 8 + tid] = 0.0f;   // sentinel el/u = 0
    featq[(size_t)NN * 256 + tid] = 0;                // sentinel feat = 0 (no fp8 NaN)
  }
}

// Padded CSR scatter (uint16 src ids: NN < 65536)
__global__ void k_scatter(const int* __restrict__ src, const int* __restrict__ dst,
                          int* __restrict__ cursor, unsigned short* __restrict__ csr_src) {
  int e = blockIdx.x * 256 + threadIdx.x;
  if (e < NE) {
    int n = dst[e];
    int pos = atomicAdd(&cursor[n], 1);
    if (pos < CAP) csr_src[n * CAP + pos] = (unsigned short)src[e];
  }
}

// bf16 MFMA GEMM: block = 64 rows x 416 cols, 4 waves; wave (rowHalf, colHalf) does
// TWO 16-row groups x 13 tiles.  A is loaded DIRECTLY from x (f32, 16x128B segments
// per fragment-pair) and converted with v_cvt_pk_bf16_f32 in-register -- no xf
// staging pass.  Ping-pong double-buffer on A and B fragments.
__global__ __launch_bounds__(256, 2) void k_gemm_mfma(
    const float* __restrict__ x, const unsigned short* __restrict__ Btf,
    const float* __restrict__ gate_m_b,
    const float* __restrict__ attn_l, const float* __restrict__ attn_r,
    unsigned char* __restrict__ featq, unsigned char* __restrict__ zq,
    float* __restrict__ xm, float* __restrict__ gx, float* __restrict__ epay,
    float* __restrict__ erv) {
  __shared__ float els[64][4][2];
  __shared__ float ers[64][4][2];
  int lane = threadIdx.x & 63;
  int wave = threadIdx.x >> 6;
  int rowHalf = wave >> 1, colHalf = wave & 1;
  int rowB = blockIdx.x * 64;
  int row0 = rowB + rowHalf * 32;
  int t0 = colHalf * 13;
  int m = lane & 15, kg = lane >> 4;
  f32x4 zero = {0.f, 0.f, 0.f, 0.f};
  f32x4 acc[2][13];
#pragma unroll
  for (int g = 0; g < 2; ++g)
#pragma unroll
    for (int t = 0; t < 13; ++t) acc[g][t] = zero;

  int r0i = row0 + m;                     // g = 0 row
  int r1i = r0i + 16;                     // g = 1 row
  if (r0i >= NN) r0i = NN - 1;            // clamp: x has exactly NN rows
  if (r1i >= NN) r1i = NN - 1;
  const float* aP0 = x + (size_t)r0i * 256 + kg * 8;
  const float* aP1 = x + (size_t)r1i * 256 + kg * 8;
  const unsigned short* bB = Btf + (size_t)(t0 * 64 + lane) * 8;

  bf16x8 aC0, aC1, aN0, aN1, bC[13], bN[13];
  aC0 = ld_a_bf16(aP0);
  aC1 = ld_a_bf16(aP1);
#pragma unroll
  for (int t = 0; t < 13; ++t)
    bC[t] = *(const bf16x8*)(bB + (size_t)t * 512);
#pragma unroll 1
  for (int kq = 0; kq < 8; kq += 2) {
    aN0 = ld_a_bf16(aP0 + (kq + 1) * 32);
    aN1 = ld_a_bf16(aP1 + (kq + 1) * 32);
#pragma unroll
    for (int t = 0; t < 13; ++t)
      bN[t] = *(const bf16x8*)(bB + ((size_t)(kq + 1) * NT + t) * 512);
#pragma unroll
    for (int t = 0; t < 13; ++t)
      acc[0][t] = __builtin_amdgcn_mfma_f32_16x16x32_bf16(aC0, bC[t], acc[0][t], 0, 0, 0);
#pragma unroll
    for (int t = 0; t < 13; ++t)
      acc[1][t] = __builtin_amdgcn_mfma_f32_16x16x32_bf16(aC1, bC[t], acc[1][t], 0, 0, 0);
    int kq2 = kq + 2 < 8 ? kq + 2 : 7;
    aC0 = ld_a_bf16(aP0 + kq2 * 32);
    aC1 = ld_a_bf16(aP1 + kq2 * 32);
#pragma unroll
    for (int t = 0; t < 13; ++t)
      bC[t] = *(const bf16x8*)(bB + ((size_t)kq2 * NT + t) * 512);
#pragma unroll
    for (int t = 0; t < 13; ++t)
      acc[0][t] = __builtin_amdgcn_mfma_f32_16x16x32_bf16(aN0, bN[t], acc[0][t], 0, 0, 0);
#pragma unroll
    for (int t = 0; t < 13; ++t)
      acc[1][t] = __builtin_amdgcn_mfma_f32_16x16x32_bf16(aN1, bN[t], acc[1][t], 0, 0, 0);
  }

  // fused el/er partials: h = m&3, o = (t0+t)*4 + (m>>2), feat tiles only
  int h = m & 3, od = m >> 2;
  float elp[2][4] = {{0,0,0,0},{0,0,0,0}}, erp[2][4] = {{0,0,0,0},{0,0,0,0}};
#pragma unroll
  for (int t = 0; t < 13; ++t) {
    if ((t0 + t) * 16 < 256) {
      int o = (t0 + t) * 4 + od;
      float al = attn_l[h * 64 + o];
      float ar = attn_r[h * 64 + o];
#pragma unroll
      for (int g = 0; g < 2; ++g)
#pragma unroll
        for (int r = 0; r < 4; ++r) {
          elp[g][r] += acc[g][t][r] * al;
          erp[g][r] += acc[g][t][r] * ar;
        }
    }
  }
#pragma unroll
  for (int g = 0; g < 2; ++g)
#pragma unroll
    for (int r = 0; r < 4; ++r) {
      elp[g][r] += __shfl_xor(elp[g][r], 4, 64); elp[g][r] += __shfl_xor(elp[g][r], 8, 64);
      erp[g][r] += __shfl_xor(erp[g][r], 4, 64); erp[g][r] += __shfl_xor(erp[g][r], 8, 64);
    }
  if (m < 4) {
#pragma unroll
    for (int g = 0; g < 2; ++g)
#pragma unroll
      for (int r = 0; r < 4; ++r) {
        els[rowHalf * 32 + g * 16 + kg * 4 + r][m][colHalf] = elp[g][r];
        ers[rowHalf * 32 + g * 16 + kg * 4 + r][m][colHalf] = erp[g][r];
      }
  }

  // epilogue stores: wave-uniform colHalf branch
#pragma unroll
  for (int g = 0; g < 2; ++g) {
    if (colHalf == 0) {
#pragma unroll
      for (int r = 0; r < 4; ++r) {
        int row = row0 + g * 16 + kg * 4 + r;
        if (row >= NN) continue;
#pragma unroll
        for (int t = 0; t < 13; ++t)
          featq[(size_t)row * 256 + t * 16 + m] = f2fp8(acc[g][t][r]);
      }
    } else {
#pragma unroll
      for (int r = 0; r < 4; ++r) {
        int row = row0 + g * 16 + kg * 4 + r;
        if (row >= NN) continue;
#pragma unroll
        for (int t = 0; t < 3; ++t)          // tiles 13..15: feat cols 208+
          featq[(size_t)row * 256 + 208 + t * 16 + m] = f2fp8(acc[g][t][r]);
#pragma unroll
        for (int t = 3; t < 7; ++t) {        // tiles 16..19: z
          int cc = (t - 3) * 16 + m;
          zq[(size_t)row * 64 + cc] = f2fp8(acc[g][t][r] + gate_m_b[cc]);
        }
#pragma unroll
        for (int t = 7; t < 11; ++t)         // tiles 20..23: xm
          xm[(size_t)row * 64 + (t - 7) * 16 + m] = acc[g][t][r];
        if (m < 4) gx[(size_t)row * 4 + m] = acc[g][11][r];                   // gx
        else if (m < 8) epay[(size_t)row * 8 + (m - 4) * 2 + 1] = acc[g][11][r];  // u
      }
    }
  }
  __syncthreads();
  int tid = threadIdx.x;
  {
    int rr = tid >> 2, h2 = tid & 3;
    int row = rowB + rr;
    if (row < NN) {
      epay[(size_t)row * 8 + h2 * 2] = els[rr][h2][0] + els[rr][h2][1];
      erv[(size_t)row * 4 + h2] = ers[rr][h2][0] + ers[rr][h2][1];
    }
  }
}

// Block = 16 nodes (4 per wave, sequential), single pass per node, 16-edge chunks.
// Uniform-row loads via readlane -> SGPR base; batched loads; packed f32x2 accum.
// nbase splits the grid into two dispatches (per-dispatch visibility in rocprof).
__global__ __launch_bounds__(256) void k_node(
    const unsigned char* __restrict__ zq, const unsigned char* __restrict__ featq,
    const float* __restrict__ epay, const float* __restrict__ er,
    const float* __restrict__ gx,
    const int* __restrict__ cursor, const unsigned short* __restrict__ csr_src,
    const float* __restrict__ gate_fn_W, const float* __restrict__ gate_fn_b,
    const unsigned short* __restrict__ mWf, const float* __restrict__ xm,
    const float* __restrict__ merge_b, float* __restrict__ out, int nbase) {
  __shared__ float WzT[4][64];             // gate_fn_W max_z-part, transposed [h][c]
  __shared__ float pbuf[4][16][4];         // [wave][edge][head]
  __shared__ unsigned short gLDS[16][72];  // gated bf16, padded stride
  int tid = threadIdx.x;
  {
    int c = tid >> 2, h = tid & 3;
    WzT[h][c] = gate_fn_W[(256 + c) * 4 + h];
  }
  __syncthreads();

  int lane = tid & 63, wave = tid >> 6;
  int hh = lane >> 4, le = lane & 15;
  int rowbase = nbase + blockIdx.x * 16;
  int nodeBase = rowbase + wave * 4;
#pragma unroll 1
  for (int i = 0; i < 4; ++i) {
    int node = nodeBase + i;
    int deg = cursor[node]; if (deg > CAP) deg = CAP;
    float gated = 0.0f;
    if (deg > 0) {
      int rs = node * CAP, re = rs + deg;
      float er_h = er[(size_t)node * 4 + hh];
      f32x2 A01 = {0.f, 0.f}, A23 = {0.f, 0.f};
      float psum = 0, usum = 0;
      float mz = -INFINITY;
      int jj = rs + le;
      int s_l = (jj < re) ? (int)csr_src[jj] : NN;   // NN = sentinel row
#pragma unroll 1
      for (int j0 = rs; j0 < re; j0 += 16) {
        // prefetch next chunk's source ids (independent -> issues early)
        int jn = j0 + 16 + le;
        int s_nx = (jn < re) ? (int)csr_src[jn] : NN;
        bool valid = (j0 + le) < re;
        float2 eu = *(const float2*)(epay + ((size_t)(unsigned)s_l << 3) + hh * 2);
        float p = valid ? __expf(leaky(eu.x + er_h)) : 0.0f;
        psum += p;
        usum += eu.y;                                // sentinel u == 0
        pbuf[wave][le][hh] = p;                      // wave-synchronous broadcast
        // batched gather: issue all loads, then decode (max MLP)
        unsigned int fvr[16];
        unsigned int zvr[16];
#pragma unroll
        for (int e2 = 0; e2 < 16; ++e2) {
          int s = rli(s_l, e2);                      // SGPR row id -> scalar base
          fvr[e2] = *(const unsigned int*)(featq + ((size_t)(unsigned)s << 8) + lane * 4);
        }
#pragma unroll
        for (int e2 = 0; e2 < 16; ++e2) {
          int s = rli(s_l, e2);
          zvr[e2] = zq[((size_t)(unsigned)s << 6) + lane];
        }
#pragma unroll
        for (int e2 = 0; e2 < 16; ++e2) {
          float4 pv = *(const float4*)pbuf[wave][e2];   // ds_read_b128, uniform addr
          f32x2 p01 = {pv.x, pv.y};
          f32x2 p23 = {pv.z, pv.w};
          A01 += p01 * fp8x2_lo(fvr[e2]);
          A23 += p23 * fp8x2_hi(fvr[e2]);
          mz = fmaxf(mz, fp8one(zvr[e2]));
        }
        s_l = s_nx;
      }
      // reduce p/u sums within each 16-lane head group
#pragma unroll
      for (int off = 1; off < 16; off <<= 1) {
        psum += __shfl_xor(psum, off, 64);
        usum += __shfl_xor(usum, off, 64);
      }
      float s0 = rlf(psum, 0),  s1 = rlf(psum, 16);
      float s2 = rlf(psum, 32), s3 = rlf(psum, 48);
      float su0 = rlf(usum, 0),  su1 = rlf(usum, 16);
      float su2 = rlf(usum, 32), su3 = rlf(usum, 48);

      // gate: sigmoid(gx + Wz·max_z + mean-part + b)
      float g[4];
#pragma unroll
      for (int h = 0; h < 4; ++h) {
        float t = mz * WzT[h][lane];
#pragma unroll
        for (int off = 32; off; off >>= 1) t += __shfl_xor(t, off, 64);
        g[h] = t;
      }
      float inv_deg = 1.0f / (float)deg;
      float4 gx4 = *(const float4*)(gx + (size_t)node * 4);
      float g0 = 1.0f / (1.0f + __expf(-(g[0] + gx4.x + su0 * inv_deg + gate_fn_b[0])));
      float g1 = 1.0f / (1.0f + __expf(-(g[1] + gx4.y + su1 * inv_deg + gate_fn_b[1])));
      float g2 = 1.0f / (1.0f + __expf(-(g[2] + gx4.z + su2 * inv_deg + gate_fn_b[2])));
      float g3 = 1.0f / (1.0f + __expf(-(g[3] + gx4.w + su3 * inv_deg + gate_fn_b[3])));
      gated = 0.25f * (g0 * A01[0] / s0 + g1 * A01[1] / s1 +
                       g2 * A23[0] / s2 + g3 * A23[1] / s3);
    }
    gLDS[wave * 4 + i][lane] = f2bf(gated);
  }
  __syncthreads();

  // fused merge: out[16 rows][64] = gated @ merge_W[256:] + xm + merge_b
  // wave w computes column tile w (cols w*16..+15); A shared from gLDS.
  int m = lane & 15, kg = lane >> 4;
  f32x4 acc = {0.f, 0.f, 0.f, 0.f};
#pragma unroll
  for (int kq = 0; kq < 2; ++kq) {
    bf16x8 a = *(const bf16x8*)(&gLDS[m][kq * 32 + kg * 8]);
    bf16x8 b = *(const bf16x8*)(mWf + (((size_t)kq * 4 + wave) * 64 + lane) * 8);
    acc = __builtin_amdgcn_mfma_f32_16x16x32_bf16(a, b, acc, 0, 0, 0);
  }
  int c = wave * 16 + m;
  float mb = merge_b[c];
#pragma unroll
  for (int r = 0; r < 4; ++r) {
    int row = rowbase + kg * 4 + r;
    out[(size_t)row * 64 + c] = acc[r] + xm[(size_t)row * 64 + c] + mb;
  }
}

extern "C" void kernel_launch(void* const* d_in, const int* in_sizes, int n_in,
                              void* d_out, int out_size, void* d_ws, size_t ws_size,
                              hipStream_t stream) {
  const float* x         = (const float*)d_in[0];
  const int*   src       = (const int*)d_in[1];
  const int*   dst       = (const int*)d_in[2];
  const float* W_gat     = (const float*)d_in[3];
  const float* attn_l    = (const float*)d_in[4];
  const float* attn_r    = (const float*)d_in[5];
  const float* gate_m_W  = (const float*)d_in[6];
  const float* gate_m_b  = (const float*)d_in[7];
  const float* gate_fn_W = (const float*)d_in[8];
  const float* gate_fn_b = (const float*)d_in[9];
  const float* merge_W   = (const float*)d_in[10];
  const float* merge_b   = (const float*)d_in[11];
  float* out = (float*)d_out;

  char* ws = (char*)d_ws;
  size_t off = 0;
  auto alloc = [&](size_t bytes) -> void* {
    off = (off + 255) & ~(size_t)255;
    void* p = ws + off;
    off += bytes;
    return p;
  };
  int* cursor    = (int*)alloc((size_t)NN * 4);
  unsigned short* csr_src = (unsigned short*)alloc((size_t)NN * CAP * 2);
  float* epay = (float*)alloc((size_t)(NN + 1) * 8 * 4);   // {el,u} x 4 heads + sentinel
  float* er   = (float*)alloc((size_t)NN * 4 * 4);
  float* gx   = (float*)alloc((size_t)NN * 4 * 4);
  float* xm   = (float*)alloc((size_t)NN * 64 * 4);
  unsigned char* zq    = (unsigned char*)alloc((size_t)(NN + 1) * 64);
  unsigned char* featq = (unsigned char*)alloc((size_t)(NN + 1) * 256);
  unsigned short* Btf    = (unsigned short*)alloc((size_t)NBT * 8 * 2);
  unsigned short* mWf    = (unsigned short*)alloc((size_t)512 * 8 * 2);

  hipMemsetAsync(cursor, 0, (size_t)NN * 4, stream);
  k_prep<<<BT_BLKS + 1, 256, 0, stream>>>(W_gat, gate_m_W, merge_W, gate_fn_W,
                                          Btf, mWf, zq, epay, featq);
  k_scatter<<<(NE + 255) / 256, 256, 0, stream>>>(src, dst, cursor, csr_src);
  k_gemm_mfma<<<(NN + 63) / 64, 256, 0, stream>>>(x, Btf, gate_m_b, attn_l, attn_r,
                                                  featq, zq, xm, gx, epay, er);
  const int HALF1 = 1563;                       // nodes 0..25007
  const int HALF2 = (NN / 16) - HALF1;          // nodes 25008..49999
  k_node<<<HALF1, 256, 0, stream>>>(zq, featq, epay, er, gx, cursor, csr_src,
                                    gate_fn_W, gate_fn_b, mWf, xm, merge_b, out, 0);
  k_node<<<HALF2, 256, 0, stream>>>(zq, featq, epay, er, gx, cursor, csr_src,
                                    gate_fn_W, gate_fn_b, mWf, xm, merge_b, out,
                                    HALF1 * 16);
}

// Round 4
// 244.744 us; speedup vs baseline: 1.1159x; 1.1159x over previous
//
#include <hip/hip_runtime.h>
#include <math.h>

#define NN 50000
#define NE 800000
// IN=256, MAP=64, H=4, O=64
#define LEAKY 0.2f
#define NT 26              // 26 column tiles of 16 (416 cols, 400 real)
#define CAP 96             // padded CSR slots/node (max deg over Poisson(16) << 96)
#define NBT (8 * NT * 64)  // Btf fragment count
#define BT_BLKS 54         // (NBT+512)/256 exactly
#define GEMM_BLKS 782      // (NN+63)/64
#define SCAT_BLKS 3125     // NE/256
#define FUSE_BLKS 3907     // GEMM_BLKS + SCAT_BLKS

typedef short bf16x8 __attribute__((ext_vector_type(8)));
typedef float f32x4 __attribute__((ext_vector_type(4)));
typedef float f32x2 __attribute__((ext_vector_type(2)));

__device__ __forceinline__ unsigned short f2bf(float f) {
  unsigned u = __float_as_uint(f);
  u += 0x7fffu + ((u >> 16) & 1u);
  return (unsigned short)(u >> 16);
}
__device__ __forceinline__ float leaky(float v) { return v > 0.0f ? v : LEAKY * v; }
__device__ __forceinline__ float rlf(float v, int l) {
  return __uint_as_float(__builtin_amdgcn_readlane(__float_as_uint(v), l));
}
__device__ __forceinline__ int rli(int v, int l) {
  return __builtin_amdgcn_readlane(v, l);
}

// packed f32->bf16 (RNE) x8 via HW cvt; returns MFMA A/B fragment
__device__ __forceinline__ bf16x8 ld_a_bf16(const float* p) {
  float4 fa = *(const float4*)p;
  float4 fb = *(const float4*)(p + 4);
  unsigned r0, r1, r2, r3;
  asm("v_cvt_pk_bf16_f32 %0, %1, %2" : "=v"(r0) : "v"(fa.x), "v"(fa.y));
  asm("v_cvt_pk_bf16_f32 %0, %1, %2" : "=v"(r1) : "v"(fa.z), "v"(fa.w));
  asm("v_cvt_pk_bf16_f32 %0, %1, %2" : "=v"(r2) : "v"(fb.x), "v"(fb.y));
  asm("v_cvt_pk_bf16_f32 %0, %1, %2" : "=v"(r3) : "v"(fb.z), "v"(fb.w));
  union { uint4 u; bf16x8 v; } c;
  c.u = make_uint4(r0, r1, r2, r3);
  return c.v;
}

// ---- fp8 e4m3fn helpers (HW cvt on gfx950; software fallback) ----
#if defined(__has_builtin)
#if __has_builtin(__builtin_amdgcn_cvt_pk_f32_fp8) && \
    __has_builtin(__builtin_amdgcn_cvt_pk_fp8_f32) && \
    __has_builtin(__builtin_amdgcn_cvt_f32_fp8)
#define FP8_HW 1
#endif
#endif

#ifdef FP8_HW
__device__ __forceinline__ unsigned char f2fp8(float v) {
  return (unsigned char)(__builtin_amdgcn_cvt_pk_fp8_f32(v, v, 0u, false) & 0xFF);
}
__device__ __forceinline__ f32x2 fp8x2_lo(unsigned int v) {
  return __builtin_amdgcn_cvt_pk_f32_fp8(v, false);   // word-select must be literal
}
__device__ __forceinline__ f32x2 fp8x2_hi(unsigned int v) {
  return __builtin_amdgcn_cvt_pk_f32_fp8(v, true);
}
__device__ __forceinline__ float fp8one(unsigned int v) {
  return __builtin_amdgcn_cvt_f32_fp8(v, 0);
}
#else
__device__ __forceinline__ unsigned char f2fp8(float f) {
  unsigned u = __float_as_uint(f);
  unsigned s = (u >> 31) << 7;
  unsigned a = u & 0x7FFFFFFFu;
  if (a >= 0x43E00000u) return (unsigned char)(s | 0x7E);
  if (a < 0x3C800000u) {
    float m = __uint_as_float(a) * 512.0f;
    int q = (int)(m + 0.5f); if (q > 7) q = 7;
    return (unsigned char)(s | q);
  }
  a += 0x7FFFFu + ((a >> 20) & 1);
  unsigned e = ((a >> 23) & 0xFF) - 120;
  if (e > 15) return (unsigned char)(s | 0x7E);
  return (unsigned char)(s | (e << 3) | ((a >> 20) & 7));
}
__device__ __forceinline__ float fp8dec1(unsigned b) {
  unsigned s = (b & 0x80u) << 24;
  unsigned em = b & 0x7Fu;
  unsigned e4 = em >> 3, m3 = em & 7;
  float v = e4 ? __uint_as_float(((e4 + 120) << 23) | (m3 << 20))
               : (float)m3 * 0.001953125f;
  return __uint_as_float(__float_as_uint(v) ^ s);
}
__device__ __forceinline__ f32x2 fp8x2_lo(unsigned int v) {
  f32x2 r; r[0] = fp8dec1(v & 0xFF); r[1] = fp8dec1((v >> 8) & 0xFF); return r;
}
__device__ __forceinline__ f32x2 fp8x2_hi(unsigned int v) {
  f32x2 r; r[0] = fp8dec1((v >> 16) & 0xFF); r[1] = fp8dec1((v >> 24) & 0xFF); return r;
}
__device__ __forceinline__ float fp8one(unsigned int v) { return fp8dec1(v & 0xFF); }
#endif

// Panel columns (416 = 26 tiles of 16):
//  c in 0..255   : feat, PERMUTED: panel col c holds W_gat column (c&3)*64 + (c>>2)
//                  so the GEMM output is featq[row][o*4+h] (o=c>>2, h=c&3)
//  c in 256..319 : gate_m_W (z)
//  c in 320..383 : merge_W[0:256] (xm)
//  c in 384..387 : gate_fn_W x-part (gx)
//  c in 388..391 : gate_fn_W mean-part (u)
//  c >= 392      : zero pad
__device__ __forceinline__ float panel_w(int col, int k,
    const float* W_gat, const float* gate_m_W, const float* merge_W,
    const float* gate_fn_W) {
  if (col < 256)      return W_gat[k * 256 + (col & 3) * 64 + (col >> 2)];
  else if (col < 320) return gate_m_W[k * 64 + (col - 256)];
  else if (col < 384) return merge_W[k * 64 + (col - 320)];
  else if (col < 388) return gate_fn_W[k * 4 + (col - 384)];
  else if (col < 392) return gate_fn_W[(320 + k) * 4 + (col - 388)];
  return 0.0f;
}

// Weight prep: Btf + mWf fragments, sentinels.
__global__ __launch_bounds__(256) void k_prep(
    const float* __restrict__ W_gat, const float* __restrict__ gate_m_W,
    const float* __restrict__ merge_W, const float* __restrict__ gate_fn_W,
    unsigned short* __restrict__ Btf, unsigned short* __restrict__ mWf,
    unsigned char* __restrict__ zq, float* __restrict__ epay,
    unsigned char* __restrict__ featq) {
  int b = blockIdx.x, tid = threadIdx.x;
  int idx = b * 256 + tid;
  if (idx < NBT) {
    int kq = idx / (NT * 64);
    int rem = idx - kq * (NT * 64);
    int t = rem >> 6, lane = rem & 63;
    int col = t * 16 + (lane & 15);
    int k = kq * 32 + (lane >> 4) * 8;
    unsigned short* o = Btf + (size_t)idx * 8;
#pragma unroll
    for (int i = 0; i < 8; ++i)
      o[i] = f2bf(panel_w(col, k + i, W_gat, gate_m_W, merge_W, gate_fn_W));
  } else if (idx < NBT + 512) {
    int idx2 = idx - NBT;
    int kq = idx2 >> 8;
    int rem = idx2 & 255;
    int t = rem >> 6, lane = rem & 63;
    int col = t * 16 + (lane & 15);
    int k = kq * 32 + ((lane >> 4) & 3) * 8;
    unsigned short* o = mWf + (size_t)idx2 * 8;
#pragma unroll
    for (int i = 0; i < 8; ++i)
      o[i] = f2bf(merge_W[(size_t)(256 + k + i) * 64 + col]);
  } else if (b == BT_BLKS) {
    if (tid < 64) zq[(size_t)NN * 64 + tid] = 0xFE;   // sentinel z = -448
    if (tid < 8) epay[(size_t)NN * 8 + tid] = 0.0f;   // sentinel el/u = 0
    featq[(size_t)NN * 256 + tid] = 0;                // sentinel feat = 0 (no fp8 NaN)
  }
}

// FUSED gemm || scatter: blockIdx%5==0 -> gemm block (782), else scatter block (3125).
// The two are data-independent; gemm is issue/latency-bound with idle memory slots,
// scatter is pure memory-latency with idle SIMDs -> co-residency overlaps them.
// Branch is block-uniform so the gemm path's __syncthreads is safe.
__global__ __launch_bounds__(256, 2) void k_gemm_scatter(
    const float* __restrict__ x, const unsigned short* __restrict__ Btf,
    const float* __restrict__ gate_m_b,
    const float* __restrict__ attn_l, const float* __restrict__ attn_r,
    unsigned char* __restrict__ featq, unsigned char* __restrict__ zq,
    float* __restrict__ xm, float* __restrict__ gx, float* __restrict__ epay,
    float* __restrict__ erv,
    const int* __restrict__ src, const int* __restrict__ dst,
    int* __restrict__ cursor, unsigned short* __restrict__ csr_src) {
  __shared__ float els[64][4][2];
  __shared__ float ers[64][4][2];
  int bq = blockIdx.x / 5, br = blockIdx.x % 5;
  if (br != 0) {
    // ---------------- scatter path ----------------
    int sIdx = bq * 4 + (br - 1);
    int e = sIdx * 256 + threadIdx.x;
    if (e < NE) {
      int n = dst[e];
      int pos = atomicAdd(&cursor[n], 1);
      if (pos < CAP) csr_src[n * CAP + pos] = (unsigned short)src[e];
    }
    return;
  }
  // ---------------- gemm path ----------------
  int lane = threadIdx.x & 63;
  int wave = threadIdx.x >> 6;
  int rowHalf = wave >> 1, colHalf = wave & 1;
  int rowB = bq * 64;
  int row0 = rowB + rowHalf * 32;
  int t0 = colHalf * 13;
  int m = lane & 15, kg = lane >> 4;
  f32x4 zero = {0.f, 0.f, 0.f, 0.f};
  f32x4 acc[2][13];
#pragma unroll
  for (int g = 0; g < 2; ++g)
#pragma unroll
    for (int t = 0; t < 13; ++t) acc[g][t] = zero;

  int r0i = row0 + m;                     // g = 0 row
  int r1i = r0i + 16;                     // g = 1 row
  if (r0i >= NN) r0i = NN - 1;            // clamp: x has exactly NN rows
  if (r1i >= NN) r1i = NN - 1;
  const float* aP0 = x + (size_t)r0i * 256 + kg * 8;
  const float* aP1 = x + (size_t)r1i * 256 + kg * 8;
  const unsigned short* bB = Btf + (size_t)(t0 * 64 + lane) * 8;

  bf16x8 aC0, aC1, aN0, aN1, bC[13], bN[13];
  aC0 = ld_a_bf16(aP0);
  aC1 = ld_a_bf16(aP1);
#pragma unroll
  for (int t = 0; t < 13; ++t)
    bC[t] = *(const bf16x8*)(bB + (size_t)t * 512);
#pragma unroll 1
  for (int kq = 0; kq < 8; kq += 2) {
    aN0 = ld_a_bf16(aP0 + (kq + 1) * 32);
    aN1 = ld_a_bf16(aP1 + (kq + 1) * 32);
#pragma unroll
    for (int t = 0; t < 13; ++t)
      bN[t] = *(const bf16x8*)(bB + ((size_t)(kq + 1) * NT + t) * 512);
#pragma unroll
    for (int t = 0; t < 13; ++t)
      acc[0][t] = __builtin_amdgcn_mfma_f32_16x16x32_bf16(aC0, bC[t], acc[0][t], 0, 0, 0);
#pragma unroll
    for (int t = 0; t < 13; ++t)
      acc[1][t] = __builtin_amdgcn_mfma_f32_16x16x32_bf16(aC1, bC[t], acc[1][t], 0, 0, 0);
    int kq2 = kq + 2 < 8 ? kq + 2 : 7;
    aC0 = ld_a_bf16(aP0 + kq2 * 32);
    aC1 = ld_a_bf16(aP1 + kq2 * 32);
#pragma unroll
    for (int t = 0; t < 13; ++t)
      bC[t] = *(const bf16x8*)(bB + ((size_t)kq2 * NT + t) * 512);
#pragma unroll
    for (int t = 0; t < 13; ++t)
      acc[0][t] = __builtin_amdgcn_mfma_f32_16x16x32_bf16(aN0, bN[t], acc[0][t], 0, 0, 0);
#pragma unroll
    for (int t = 0; t < 13; ++t)
      acc[1][t] = __builtin_amdgcn_mfma_f32_16x16x32_bf16(aN1, bN[t], acc[1][t], 0, 0, 0);
  }

  // fused el/er partials: h = m&3, o = (t0+t)*4 + (m>>2), feat tiles only
  int h = m & 3, od = m >> 2;
  float elp[2][4] = {{0,0,0,0},{0,0,0,0}}, erp[2][4] = {{0,0,0,0},{0,0,0,0}};
#pragma unroll
  for (int t = 0; t < 13; ++t) {
    if ((t0 + t) * 16 < 256) {
      int o = (t0 + t) * 4 + od;
      float al = attn_l[h * 64 + o];
      float ar = attn_r[h * 64 + o];
#pragma unroll
      for (int g = 0; g < 2; ++g)
#pragma unroll
        for (int r = 0; r < 4; ++r) {
          elp[g][r] += acc[g][t][r] * al;
          erp[g][r] += acc[g][t][r] * ar;
        }
    }
  }
#pragma unroll
  for (int g = 0; g < 2; ++g)
#pragma unroll
    for (int r = 0; r < 4; ++r) {
      elp[g][r] += __shfl_xor(elp[g][r], 4, 64); elp[g][r] += __shfl_xor(elp[g][r], 8, 64);
      erp[g][r] += __shfl_xor(erp[g][r], 4, 64); erp[g][r] += __shfl_xor(erp[g][r], 8, 64);
    }
  if (m < 4) {
#pragma unroll
    for (int g = 0; g < 2; ++g)
#pragma unroll
      for (int r = 0; r < 4; ++r) {
        els[rowHalf * 32 + g * 16 + kg * 4 + r][m][colHalf] = elp[g][r];
        ers[rowHalf * 32 + g * 16 + kg * 4 + r][m][colHalf] = erp[g][r];
      }
  }

  // epilogue stores: wave-uniform colHalf branch
#pragma unroll
  for (int g = 0; g < 2; ++g) {
    if (colHalf == 0) {
#pragma unroll
      for (int r = 0; r < 4; ++r) {
        int row = row0 + g * 16 + kg * 4 + r;
        if (row >= NN) continue;
#pragma unroll
        for (int t = 0; t < 13; ++t)
          featq[(size_t)row * 256 + t * 16 + m] = f2fp8(acc[g][t][r]);
      }
    } else {
#pragma unroll
      for (int r = 0; r < 4; ++r) {
        int row = row0 + g * 16 + kg * 4 + r;
        if (row >= NN) continue;
#pragma unroll
        for (int t = 0; t < 3; ++t)          // tiles 13..15: feat cols 208+
          featq[(size_t)row * 256 + 208 + t * 16 + m] = f2fp8(acc[g][t][r]);
#pragma unroll
        for (int t = 3; t < 7; ++t) {        // tiles 16..19: z
          int cc = (t - 3) * 16 + m;
          zq[(size_t)row * 64 + cc] = f2fp8(acc[g][t][r] + gate_m_b[cc]);
        }
#pragma unroll
        for (int t = 7; t < 11; ++t)         // tiles 20..23: xm
          xm[(size_t)row * 64 + (t - 7) * 16 + m] = acc[g][t][r];
        if (m < 4) gx[(size_t)row * 4 + m] = acc[g][11][r];                   // gx
        else if (m < 8) epay[(size_t)row * 8 + (m - 4) * 2 + 1] = acc[g][11][r];  // u
      }
    }
  }
  __syncthreads();
  int tid = threadIdx.x;
  {
    int rr = tid >> 2, h2 = tid & 3;
    int row = rowB + rr;
    if (row < NN) {
      epay[(size_t)row * 8 + h2 * 2] = els[rr][h2][0] + els[rr][h2][1];
      erv[(size_t)row * 4 + h2] = ers[rr][h2][0] + ers[rr][h2][1];
    }
  }
}

// Block = 16 nodes (4 per wave, sequential), single pass per node, 16-edge chunks.
// Uniform-row loads via readlane -> SGPR base; batched loads; packed f32x2 accum.
__global__ __launch_bounds__(256) void k_node(
    const unsigned char* __restrict__ zq, const unsigned char* __restrict__ featq,
    const float* __restrict__ epay, const float* __restrict__ er,
    const float* __restrict__ gx,
    const int* __restrict__ cursor, const unsigned short* __restrict__ csr_src,
    const float* __restrict__ gate_fn_W, const float* __restrict__ gate_fn_b,
    const unsigned short* __restrict__ mWf, const float* __restrict__ xm,
    const float* __restrict__ merge_b, float* __restrict__ out) {
  __shared__ float WzT[4][64];             // gate_fn_W max_z-part, transposed [h][c]
  __shared__ float pbuf[4][16][4];         // [wave][edge][head]
  __shared__ unsigned short gLDS[16][72];  // gated bf16, padded stride
  int tid = threadIdx.x;
  {
    int c = tid >> 2, h = tid & 3;
    WzT[h][c] = gate_fn_W[(256 + c) * 4 + h];
  }
  __syncthreads();

  int lane = tid & 63, wave = tid >> 6;
  int hh = lane >> 4, le = lane & 15;
  int rowbase = blockIdx.x * 16;
  int nodeBase = rowbase + wave * 4;
#pragma unroll 1
  for (int i = 0; i < 4; ++i) {
    int node = nodeBase + i;
    int deg = cursor[node]; if (deg > CAP) deg = CAP;
    float gated = 0.0f;
    if (deg > 0) {
      int rs = node * CAP, re = rs + deg;
      float er_h = er[(size_t)node * 4 + hh];
      f32x2 A01 = {0.f, 0.f}, A23 = {0.f, 0.f};
      float psum = 0, usum = 0;
      float mz = -INFINITY;
      int jj = rs + le;
      int s_l = (jj < re) ? (int)csr_src[jj] : NN;   // NN = sentinel row
#pragma unroll 1
      for (int j0 = rs; j0 < re; j0 += 16) {
        // prefetch next chunk's source ids (independent -> issues early)
        int jn = j0 + 16 + le;
        int s_nx = (jn < re) ? (int)csr_src[jn] : NN;
        bool valid = (j0 + le) < re;
        float2 eu = *(const float2*)(epay + ((size_t)(unsigned)s_l << 3) + hh * 2);
        float p = valid ? __expf(leaky(eu.x + er_h)) : 0.0f;
        psum += p;
        usum += eu.y;                                // sentinel u == 0
        pbuf[wave][le][hh] = p;                      // wave-synchronous broadcast
        // batched gather: issue all loads, then decode (max MLP)
        unsigned int fvr[16];
        unsigned int zvr[16];
#pragma unroll
        for (int e2 = 0; e2 < 16; ++e2) {
          int s = rli(s_l, e2);                      // SGPR row id -> scalar base
          fvr[e2] = *(const unsigned int*)(featq + ((size_t)(unsigned)s << 8) + lane * 4);
        }
#pragma unroll
        for (int e2 = 0; e2 < 16; ++e2) {
          int s = rli(s_l, e2);
          zvr[e2] = zq[((size_t)(unsigned)s << 6) + lane];
        }
#pragma unroll
        for (int e2 = 0; e2 < 16; ++e2) {
          float4 pv = *(const float4*)pbuf[wave][e2];   // ds_read_b128, uniform addr
          f32x2 p01 = {pv.x, pv.y};
          f32x2 p23 = {pv.z, pv.w};
          A01 += p01 * fp8x2_lo(fvr[e2]);
          A23 += p23 * fp8x2_hi(fvr[e2]);
          mz = fmaxf(mz, fp8one(zvr[e2]));
        }
        s_l = s_nx;
      }
      // reduce p/u sums within each 16-lane head group
#pragma unroll
      for (int off = 1; off < 16; off <<= 1) {
        psum += __shfl_xor(psum, off, 64);
        usum += __shfl_xor(usum, off, 64);
      }
      float s0 = rlf(psum, 0),  s1 = rlf(psum, 16);
      float s2 = rlf(psum, 32), s3 = rlf(psum, 48);
      float su0 = rlf(usum, 0),  su1 = rlf(usum, 16);
      float su2 = rlf(usum, 32), su3 = rlf(usum, 48);

      // gate: sigmoid(gx + Wz·max_z + mean-part + b)
      float g[4];
#pragma unroll
      for (int h = 0; h < 4; ++h) {
        float t = mz * WzT[h][lane];
#pragma unroll
        for (int off = 32; off; off >>= 1) t += __shfl_xor(t, off, 64);
        g[h] = t;
      }
      float inv_deg = 1.0f / (float)deg;
      float4 gx4 = *(const float4*)(gx + (size_t)node * 4);
      float g0 = 1.0f / (1.0f + __expf(-(g[0] + gx4.x + su0 * inv_deg + gate_fn_b[0])));
      float g1 = 1.0f / (1.0f + __expf(-(g[1] + gx4.y + su1 * inv_deg + gate_fn_b[1])));
      float g2 = 1.0f / (1.0f + __expf(-(g[2] + gx4.z + su2 * inv_deg + gate_fn_b[2])));
      float g3 = 1.0f / (1.0f + __expf(-(g[3] + gx4.w + su3 * inv_deg + gate_fn_b[3])));
      gated = 0.25f * (g0 * A01[0] / s0 + g1 * A01[1] / s1 +
                       g2 * A23[0] / s2 + g3 * A23[1] / s3);
    }
    gLDS[wave * 4 + i][lane] = f2bf(gated);
  }
  __syncthreads();

  // fused merge: out[16 rows][64] = gated @ merge_W[256:] + xm + merge_b
  // wave w computes column tile w (cols w*16..+15); A shared from gLDS.
  int m = lane & 15, kg = lane >> 4;
  f32x4 acc = {0.f, 0.f, 0.f, 0.f};
#pragma unroll
  for (int kq = 0; kq < 2; ++kq) {
    bf16x8 a = *(const bf16x8*)(&gLDS[m][kq * 32 + kg * 8]);
    bf16x8 b = *(const bf16x8*)(mWf + (((size_t)kq * 4 + wave) * 64 + lane) * 8);
    acc = __builtin_amdgcn_mfma_f32_16x16x32_bf16(a, b, acc, 0, 0, 0);
  }
  int c = wave * 16 + m;
  float mb = merge_b[c];
#pragma unroll
  for (int r = 0; r < 4; ++r) {
    int row = rowbase + kg * 4 + r;
    out[(size_t)row * 64 + c] = acc[r] + xm[(size_t)row * 64 + c] + mb;
  }
}

extern "C" void kernel_launch(void* const* d_in, const int* in_sizes, int n_in,
                              void* d_out, int out_size, void* d_ws, size_t ws_size,
                              hipStream_t stream) {
  const float* x         = (const float*)d_in[0];
  const int*   src       = (const int*)d_in[1];
  const int*   dst       = (const int*)d_in[2];
  const float* W_gat     = (const float*)d_in[3];
  const float* attn_l    = (const float*)d_in[4];
  const float* attn_r    = (const float*)d_in[5];
  const float* gate_m_W  = (const float*)d_in[6];
  const float* gate_m_b  = (const float*)d_in[7];
  const float* gate_fn_W = (const float*)d_in[8];
  const float* gate_fn_b = (const float*)d_in[9];
  const float* merge_W   = (const float*)d_in[10];
  const float* merge_b   = (const float*)d_in[11];
  float* out = (float*)d_out;

  char* ws = (char*)d_ws;
  size_t off = 0;
  auto alloc = [&](size_t bytes) -> void* {
    off = (off + 255) & ~(size_t)255;
    void* p = ws + off;
    off += bytes;
    return p;
  };
  int* cursor    = (int*)alloc((size_t)NN * 4);
  unsigned short* csr_src = (unsigned short*)alloc((size_t)NN * CAP * 2);
  float* epay = (float*)alloc((size_t)(NN + 1) * 8 * 4);   // {el,u} x 4 heads + sentinel
  float* er   = (float*)alloc((size_t)NN * 4 * 4);
  float* gx   = (float*)alloc((size_t)NN * 4 * 4);
  float* xm   = (float*)alloc((size_t)NN * 64 * 4);
  unsigned char* zq    = (unsigned char*)alloc((size_t)(NN + 1) * 64);
  unsigned char* featq = (unsigned char*)alloc((size_t)(NN + 1) * 256);
  unsigned short* Btf    = (unsigned short*)alloc((size_t)NBT * 8 * 2);
  unsigned short* mWf    = (unsigned short*)alloc((size_t)512 * 8 * 2);

  hipMemsetAsync(cursor, 0, (size_t)NN * 4, stream);
  k_prep<<<BT_BLKS + 1, 256, 0, stream>>>(W_gat, gate_m_W, merge_W, gate_fn_W,
                                          Btf, mWf, zq, epay, featq);
  k_gemm_scatter<<<FUSE_BLKS, 256, 0, stream>>>(x, Btf, gate_m_b, attn_l, attn_r,
                                                featq, zq, xm, gx, epay, er,
                                                src, dst, cursor, csr_src);
  k_node<<<NN / 16, 256, 0, stream>>>(zq, featq, epay, er, gx, cursor, csr_src,
                                      gate_fn_W, gate_fn_b, mWf, xm, merge_b, out);
}